// Round 1
// baseline (186.095 us; speedup 1.0000x reference)
//
#include <hip/hip_runtime.h>
#include <hip/hip_bf16.h>

#define NTOK 32768
#define NE   1024
#define DD   256
#define BM   32

typedef __attribute__((ext_vector_type(4))) float  f32x4;
typedef __attribute__((ext_vector_type(8))) short  bf16x8;

// ---- prep: emb fp32 -> bf16 copy + row norms (fp32) ----
__global__ __launch_bounds__(256) void prep_emb_kernel(
    const float* __restrict__ emb, __hip_bfloat16* __restrict__ emb_bf,
    float* __restrict__ en)
{
    const int t = threadIdx.x;
    const int row = blockIdx.x * 4 + (t >> 6);   // one wave per row
    const int q = t & 63;                        // float4 index within row
    f32x4 v = *(const f32x4*)(emb + (size_t)row * DD + q * 4);
    float ss = v.x * v.x + v.y * v.y + v.z * v.z + v.w * v.w;
#pragma unroll
    for (int off = 32; off; off >>= 1) ss += __shfl_xor(ss, off, 64);
    alignas(8) __hip_bfloat16 h[4];
    h[0] = __float2bfloat16(v.x); h[1] = __float2bfloat16(v.y);
    h[2] = __float2bfloat16(v.z); h[3] = __float2bfloat16(v.w);
    *(short4*)(emb_bf + (size_t)row * DD + q * 4) = *(const short4*)h;
    if (q == 0) en[row] = ss;
}

// ---- main: fused dist-GEMM + exp + row softmax ----
// block = 512 threads (8 waves as 2 row-groups x 4 col-groups)
// tile  = 32 rows x 1024 cols, K = 256
__global__ __launch_bounds__(512) void sq_main_kernel(
    const float* __restrict__ z, const __hip_bfloat16* __restrict__ emb_bf,
    const float* __restrict__ en, float* __restrict__ out)
{
    __shared__ alignas(16) __hip_bfloat16 za[BM][DD + 8];  // +8 bf16 pad: 2-way max
    __shared__ float zn_s[BM];
    __shared__ float red[2][BM][4];

    const int t  = threadIdx.x;
    const int n0 = blockIdx.x * BM;
    const int w  = t >> 6;     // wave id 0..7
    const int l  = t & 63;     // lane

    // ---- stage z tile: fp32 load, norms in fp32, bf16 to LDS ----
#pragma unroll
    for (int p = 0; p < 4; ++p) {
        const int r = p * 8 + w;        // one wave per row per pass
        const int q = l;
        f32x4 v = *(const f32x4*)(z + (size_t)(n0 + r) * DD + q * 4);
        float ss = v.x * v.x + v.y * v.y + v.z * v.z + v.w * v.w;
#pragma unroll
        for (int off = 32; off; off >>= 1) ss += __shfl_xor(ss, off, 64);
        if (q == 0) zn_s[r] = ss;
        alignas(8) __hip_bfloat16 h[4];
        h[0] = __float2bfloat16(v.x); h[1] = __float2bfloat16(v.y);
        h[2] = __float2bfloat16(v.z); h[3] = __float2bfloat16(v.w);
        *(short4*)&za[r][q * 4] = *(const short4*)h;
    }
    __syncthreads();

    const int wr = w >> 2, wc = w & 3;    // wave row-group / col-group
    const int lr = l & 15, lg = l >> 4;   // lane row(col) id / k-group

    // ---- A fragments: 16 rows x full K in registers ----
    bf16x8 afrag[8];
#pragma unroll
    for (int kk = 0; kk < 8; ++kk)
        afrag[kk] = *(const bf16x8*)&za[wr * 16 + lr][kk * 32 + lg * 8];

    // ---- GEMM: acc[j] = z_tile . emb^T  (16 col-tiles of 16) ----
    f32x4 acc[16];
#pragma unroll
    for (int j = 0; j < 16; ++j) acc[j] = (f32x4){0.f, 0.f, 0.f, 0.f};

    const __hip_bfloat16* bbase = emb_bf + (size_t)(wc * 256 + lr) * DD + lg * 8;
#pragma unroll
    for (int j = 0; j < 16; ++j) {
#pragma unroll
        for (int kk = 0; kk < 8; ++kk) {
            bf16x8 b = *(const bf16x8*)(bbase + (size_t)j * 16 * DD + kk * 32);
            acc[j] = __builtin_amdgcn_mfma_f32_16x16x32_bf16(afrag[kk], b, acc[j], 0, 0, 0);
        }
    }

    // ---- epilogue: s = exp(-d*10)*10; C/D map: col=lane&15, row=(lane>>4)*4+reg ----
    float zr[4];
#pragma unroll
    for (int r = 0; r < 4; ++r) zr[r] = zn_s[wr * 16 + lg * 4 + r];

    float m[4] = {-1e30f, -1e30f, -1e30f, -1e30f};
#pragma unroll
    for (int j = 0; j < 16; ++j) {
        const float ecol = en[wc * 256 + j * 16 + lr];
#pragma unroll
        for (int r = 0; r < 4; ++r) {
            const float d = zr[r] + ecol - 2.0f * acc[j][r];
            const float s = expf(-d * 10.0f) * 10.0f;
            acc[j][r] = s;
            m[r] = fmaxf(m[r], s);
        }
    }
    // row-max across the 16 lanes sharing lg
#pragma unroll
    for (int off = 1; off < 16; off <<= 1)
#pragma unroll
        for (int r = 0; r < 4; ++r) m[r] = fmaxf(m[r], __shfl_xor(m[r], off, 64));
    if (lr == 0)
#pragma unroll
        for (int r = 0; r < 4; ++r) red[0][wr * 16 + lg * 4 + r][wc] = m[r];
    __syncthreads();

    float gm[4];
#pragma unroll
    for (int r = 0; r < 4; ++r) {
        const float* p = red[0][wr * 16 + lg * 4 + r];
        gm[r] = fmaxf(fmaxf(p[0], p[1]), fmaxf(p[2], p[3]));
    }

    float sum[4] = {0.f, 0.f, 0.f, 0.f};
#pragma unroll
    for (int j = 0; j < 16; ++j)
#pragma unroll
        for (int r = 0; r < 4; ++r) {
            const float e = expf(acc[j][r] - gm[r]);
            acc[j][r] = e;
            sum[r] += e;
        }
#pragma unroll
    for (int off = 1; off < 16; off <<= 1)
#pragma unroll
        for (int r = 0; r < 4; ++r) sum[r] += __shfl_xor(sum[r], off, 64);
    if (lr == 0)
#pragma unroll
        for (int r = 0; r < 4; ++r) red[1][wr * 16 + lg * 4 + r][wc] = sum[r];
    __syncthreads();

    float inv[4];
#pragma unroll
    for (int r = 0; r < 4; ++r) {
        const float* p = red[1][wr * 16 + lg * 4 + r];
        inv[r] = 1.0f / (p[0] + p[1] + p[2] + p[3]);
    }

    // ---- store: per (j,r) a wave writes 4 x 64B contiguous segments ----
#pragma unroll
    for (int j = 0; j < 16; ++j) {
        const int col = wc * 256 + j * 16 + lr;
#pragma unroll
        for (int r = 0; r < 4; ++r) {
            const int row = wr * 16 + lg * 4 + r;
            out[(size_t)(n0 + row) * NE + col] = acc[j][r] * inv[r];
        }
    }
}

extern "C" void kernel_launch(void* const* d_in, const int* in_sizes, int n_in,
                              void* d_out, int out_size, void* d_ws, size_t ws_size,
                              hipStream_t stream) {
    (void)in_sizes; (void)n_in; (void)out_size; (void)ws_size;
    const float* z   = (const float*)d_in[0];
    const float* emb = (const float*)d_in[1];
    float* out = (float*)d_out;
    __hip_bfloat16* emb_bf = (__hip_bfloat16*)d_ws;
    float* en = (float*)((char*)d_ws + (size_t)NE * DD * sizeof(__hip_bfloat16));

    hipLaunchKernelGGL(prep_emb_kernel, dim3(NE / 4), dim3(256), 0, stream,
                       emb, emb_bf, en);
    hipLaunchKernelGGL(sq_main_kernel, dim3(NTOK / BM), dim3(512), 0, stream,
                       z, emb_bf, en, out);
}

// Round 2
// 136.127 us; speedup vs baseline: 1.3671x; 1.3671x over previous
//
#include <hip/hip_runtime.h>
#include <hip/hip_bf16.h>

#define NTOK 32768
#define NE   1024
#define DD   256
#define BM   16

typedef __attribute__((ext_vector_type(4))) float  f32x4;
typedef __attribute__((ext_vector_type(8))) short  bf16x8;

// ---- prep: emb_bf = bf16(-2*emb), en10 = -10*||e||^2 ----
__global__ __launch_bounds__(256) void prep_emb_kernel(
    const float* __restrict__ emb, __hip_bfloat16* __restrict__ emb_bf,
    float* __restrict__ en10)
{
    const int t = threadIdx.x;
    const int row = blockIdx.x * 4 + (t >> 6);   // one wave per row
    const int q = t & 63;                        // float4 index within row
    f32x4 v = *(const f32x4*)(emb + (size_t)row * DD + q * 4);
    float ss = v.x * v.x + v.y * v.y + v.z * v.z + v.w * v.w;
#pragma unroll
    for (int off = 32; off; off >>= 1) ss += __shfl_xor(ss, off, 64);
    alignas(8) __hip_bfloat16 h[4];
    h[0] = __float2bfloat16(-2.f * v.x); h[1] = __float2bfloat16(-2.f * v.y);
    h[2] = __float2bfloat16(-2.f * v.z); h[3] = __float2bfloat16(-2.f * v.w);
    *(short4*)(emb_bf + (size_t)row * DD + q * 4) = *(const short4*)h;
    if (q == 0) en10[row] = -10.f * ss;
}

// ---- main: fused dist-GEMM + double-exp + row softmax (no max pass) ----
// block = 512 threads (8 waves, each owns 128 cols); tile = 16 rows x 1024 cols
__global__ __launch_bounds__(512) void sq_main_kernel(
    const float* __restrict__ z, const __hip_bfloat16* __restrict__ embm2,
    const float* __restrict__ en10, float* __restrict__ out)
{
    __shared__ alignas(16) __hip_bfloat16 za[BM][DD + 8];
    __shared__ float zn10_s[BM];
    __shared__ float red[BM][8];

    const int t  = threadIdx.x;
    const int n0 = blockIdx.x * BM;
    const int w  = t >> 6;     // wave id 0..7
    const int l  = t & 63;     // lane

    // ---- stage z tile: fp32 load, -10*norm, bf16 to LDS (2 passes, 1 row/wave) ----
#pragma unroll
    for (int p = 0; p < 2; ++p) {
        const int r = p * 8 + w;
        f32x4 v = *(const f32x4*)(z + (size_t)(n0 + r) * DD + l * 4);
        float ss = v.x * v.x + v.y * v.y + v.z * v.z + v.w * v.w;
#pragma unroll
        for (int off = 32; off; off >>= 1) ss += __shfl_xor(ss, off, 64);
        if (l == 0) zn10_s[r] = -10.f * ss;
        alignas(8) __hip_bfloat16 h[4];
        h[0] = __float2bfloat16(v.x); h[1] = __float2bfloat16(v.y);
        h[2] = __float2bfloat16(v.z); h[3] = __float2bfloat16(v.w);
        *(short4*)&za[r][l * 4] = *(const short4*)h;
    }
    __syncthreads();

    const int lr = l & 15, lg = l >> 4;   // A-row / k-group (and B-col / k-group)

    // ---- A fragments: all 16 rows x full K in registers (32 VGPR) ----
    bf16x8 afrag[8];
#pragma unroll
    for (int kk = 0; kk < 8; ++kk)
        afrag[kk] = *(const bf16x8*)&za[lr][kk * 32 + lg * 8];

    // ---- GEMM: acc[j] = z_tile . (-2*emb)^T over this wave's 128 cols ----
    f32x4 acc[8];
#pragma unroll
    for (int j = 0; j < 8; ++j) acc[j] = (f32x4){0.f, 0.f, 0.f, 0.f};

    const __hip_bfloat16* bbase = embm2 + (size_t)(w * 128 + lr) * DD + lg * 8;
#pragma unroll
    for (int j = 0; j < 8; ++j) {
#pragma unroll
        for (int kk = 0; kk < 8; ++kk) {
            bf16x8 b = *(const bf16x8*)(bbase + (size_t)j * 16 * DD + kk * 32);
            acc[j] = __builtin_amdgcn_mfma_f32_16x16x32_bf16(afrag[kk], b, acc[j], 0, 0, 0);
        }
    }

    // ---- epilogue: t = -10*d = zn10 + en10 - 10*acc ; u = 10*exp(t) ; e = exp(u) ----
    // u in (0,10] guaranteed (d >= 0) -> no max subtraction needed.
    float zr10[4];
#pragma unroll
    for (int r = 0; r < 4; ++r) zr10[r] = zn10_s[lg * 4 + r];

    float sum[4] = {0.f, 0.f, 0.f, 0.f};
#pragma unroll
    for (int j = 0; j < 8; ++j) {
        const float ec10 = en10[w * 128 + j * 16 + lr];
#pragma unroll
        for (int r = 0; r < 4; ++r) {
            const float tt = fmaf(-10.0f, acc[j][r], zr10[r] + ec10);
            const float u  = 10.0f * __expf(tt);
            const float e  = __expf(u);
            acc[j][r] = e;
            sum[r] += e;
        }
    }
    // sum across the 16 lanes of this k-group (butterfly; stays within lg group)
#pragma unroll
    for (int off = 1; off < 16; off <<= 1)
#pragma unroll
        for (int r = 0; r < 4; ++r) sum[r] += __shfl_xor(sum[r], off, 64);
    if (lr == 0)
#pragma unroll
        for (int r = 0; r < 4; ++r) red[lg * 4 + r][w] = sum[r];
    __syncthreads();

    float inv[4];
#pragma unroll
    for (int r = 0; r < 4; ++r) {
        const float* p = red[lg * 4 + r];
        inv[r] = 1.0f / (((p[0] + p[1]) + (p[2] + p[3])) +
                         ((p[4] + p[5]) + (p[6] + p[7])));
    }

    // ---- store: per (j,r) a wave writes 4 x 64B contiguous segments ----
#pragma unroll
    for (int j = 0; j < 8; ++j) {
        const int col = w * 128 + j * 16 + lr;
#pragma unroll
        for (int r = 0; r < 4; ++r) {
            const int row = lg * 4 + r;
            out[(size_t)(n0 + row) * NE + col] = acc[j][r] * inv[r];
        }
    }
}

extern "C" void kernel_launch(void* const* d_in, const int* in_sizes, int n_in,
                              void* d_out, int out_size, void* d_ws, size_t ws_size,
                              hipStream_t stream) {
    (void)in_sizes; (void)n_in; (void)out_size; (void)ws_size;
    const float* z   = (const float*)d_in[0];
    const float* emb = (const float*)d_in[1];
    float* out = (float*)d_out;
    __hip_bfloat16* emb_bf = (__hip_bfloat16*)d_ws;
    float* en10 = (float*)((char*)d_ws + (size_t)NE * DD * sizeof(__hip_bfloat16));

    hipLaunchKernelGGL(prep_emb_kernel, dim3(NE / 4), dim3(256), 0, stream,
                       emb, emb_bf, en10);
    hipLaunchKernelGGL(sq_main_kernel, dim3(NTOK / BM), dim3(512), 0, stream,
                       z, emb_bf, en10, out);
}

// Round 3
// 135.773 us; speedup vs baseline: 1.3706x; 1.0026x over previous
//
#include <hip/hip_runtime.h>
#include <hip/hip_bf16.h>

#define NTOK 32768
#define NE   1024
#define DD   256
#define BM   16

typedef __attribute__((ext_vector_type(4))) float  f32x4;
typedef __attribute__((ext_vector_type(8))) short  bf16x8;

// ---- prep: emb_bf = bf16(-2*emb), en10 = -10*||e||^2 ----
__global__ __launch_bounds__(256) void prep_emb_kernel(
    const float* __restrict__ emb, __hip_bfloat16* __restrict__ emb_bf,
    float* __restrict__ en10)
{
    const int t = threadIdx.x;
    const int row = blockIdx.x * 4 + (t >> 6);   // one wave per row
    const int q = t & 63;                        // float4 index within row
    f32x4 v = *(const f32x4*)(emb + (size_t)row * DD + q * 4);
    float ss = v.x * v.x + v.y * v.y + v.z * v.z + v.w * v.w;
#pragma unroll
    for (int off = 32; off; off >>= 1) ss += __shfl_xor(ss, off, 64);
    alignas(8) __hip_bfloat16 h[4];
    h[0] = __float2bfloat16(-2.f * v.x); h[1] = __float2bfloat16(-2.f * v.y);
    h[2] = __float2bfloat16(-2.f * v.z); h[3] = __float2bfloat16(-2.f * v.w);
    *(short4*)(emb_bf + (size_t)row * DD + q * 4) = *(const short4*)h;
    if (q == 0) en10[row] = -10.f * ss;
}

// ---- main: fused dist-GEMM + double-exp + row softmax ----
// block = 1024 threads (16 waves); tile = 16 rows x 1024 cols;
// wave w owns cols [w*64, w*64+64). Target <=64 unified regs -> 8 waves/SIMD.
__global__ __launch_bounds__(1024, 8) void sq_main_kernel(
    const float* __restrict__ z, const __hip_bfloat16* __restrict__ embm2,
    const float* __restrict__ en10, float* __restrict__ out)
{
    __shared__ alignas(16) __hip_bfloat16 za[BM][DD + 8];
    __shared__ float zn10_s[BM];
    __shared__ float red[BM][16];

    const int t  = threadIdx.x;
    const int n0 = blockIdx.x * BM;
    const int w  = t >> 6;     // wave id 0..15  (stages row w; owns col block w)
    const int l  = t & 63;     // lane

    // ---- stage z tile: wave w stages row w (fp32 load, -10*norm, bf16 to LDS) ----
    {
        f32x4 v = *(const f32x4*)(z + (size_t)(n0 + w) * DD + l * 4);
        float ss = v.x * v.x + v.y * v.y + v.z * v.z + v.w * v.w;
#pragma unroll
        for (int off = 32; off; off >>= 1) ss += __shfl_xor(ss, off, 64);
        if (l == 0) zn10_s[w] = -10.f * ss;
        alignas(8) __hip_bfloat16 h[4];
        h[0] = __float2bfloat16(v.x); h[1] = __float2bfloat16(v.y);
        h[2] = __float2bfloat16(v.z); h[3] = __float2bfloat16(v.w);
        *(short4*)&za[w][l * 4] = *(const short4*)h;
    }
    __syncthreads();

    const int lr = l & 15, lg = l >> 4;   // A-row (B-col) / k-group

    // ---- A fragments: all 16 rows x full K in registers (32 VGPR) ----
    bf16x8 afrag[8];
#pragma unroll
    for (int kk = 0; kk < 8; ++kk)
        afrag[kk] = *(const bf16x8*)&za[lr][kk * 32 + lg * 8];

    // ---- GEMM: acc[j] = z_tile . (-2*emb)^T over this wave's 64 cols ----
    f32x4 acc[4];
#pragma unroll
    for (int j = 0; j < 4; ++j) acc[j] = (f32x4){0.f, 0.f, 0.f, 0.f};

    const __hip_bfloat16* bbase = embm2 + (size_t)(w * 64 + lr) * DD + lg * 8;
#pragma unroll
    for (int j = 0; j < 4; ++j) {
#pragma unroll
        for (int kk = 0; kk < 8; ++kk) {
            bf16x8 b = *(const bf16x8*)(bbase + (size_t)j * 16 * DD + kk * 32);
            acc[j] = __builtin_amdgcn_mfma_f32_16x16x32_bf16(afrag[kk], b, acc[j], 0, 0, 0);
        }
    }

    // ---- epilogue: tt = -10*d ; u = 10*exp(tt) ; e = exp(u) ; u in (0,10] ----
    float zr10[4];
#pragma unroll
    for (int r = 0; r < 4; ++r) zr10[r] = zn10_s[lg * 4 + r];

    float sum[4] = {0.f, 0.f, 0.f, 0.f};
#pragma unroll
    for (int j = 0; j < 4; ++j) {
        const float ec10 = en10[w * 64 + j * 16 + lr];
#pragma unroll
        for (int r = 0; r < 4; ++r) {
            const float tt = fmaf(-10.0f, acc[j][r], zr10[r] + ec10);
            const float u  = 10.0f * __expf(tt);
            const float e  = __expf(u);
            acc[j][r] = e;
            sum[r] += e;
        }
    }
    // sum across the 16 lanes sharing lg (butterfly within 16-lane groups)
#pragma unroll
    for (int off = 1; off < 16; off <<= 1)
#pragma unroll
        for (int r = 0; r < 4; ++r) sum[r] += __shfl_xor(sum[r], off, 64);
    if (lr == 0)
#pragma unroll
        for (int r = 0; r < 4; ++r) red[lg * 4 + r][w] = sum[r];
    __syncthreads();

    float inv[4];
#pragma unroll
    for (int r = 0; r < 4; ++r) {
        const float* p = red[lg * 4 + r];
        float s = 0.f;
#pragma unroll
        for (int q = 0; q < 16; ++q) s += p[q];
        inv[r] = 1.0f / s;
    }

    // ---- store: per (j,r) a wave writes 4 x 64B contiguous segments ----
#pragma unroll
    for (int j = 0; j < 4; ++j) {
        const int col = w * 64 + j * 16 + lr;
#pragma unroll
        for (int r = 0; r < 4; ++r) {
            const int row = lg * 4 + r;
            out[(size_t)(n0 + row) * NE + col] = acc[j][r] * inv[r];
        }
    }
}

extern "C" void kernel_launch(void* const* d_in, const int* in_sizes, int n_in,
                              void* d_out, int out_size, void* d_ws, size_t ws_size,
                              hipStream_t stream) {
    (void)in_sizes; (void)n_in; (void)out_size; (void)ws_size;
    const float* z   = (const float*)d_in[0];
    const float* emb = (const float*)d_in[1];
    float* out = (float*)d_out;
    __hip_bfloat16* emb_bf = (__hip_bfloat16*)d_ws;
    float* en10 = (float*)((char*)d_ws + (size_t)NE * DD * sizeof(__hip_bfloat16));

    hipLaunchKernelGGL(prep_emb_kernel, dim3(NE / 4), dim3(256), 0, stream,
                       emb, emb_bf, en10);
    hipLaunchKernelGGL(sq_main_kernel, dim3(NTOK / BM), dim3(1024), 0, stream,
                       z, emb_bf, en10, out);
}

// Round 4
// 69.347 us; speedup vs baseline: 2.6835x; 1.9579x over previous
//
#include <hip/hip_runtime.h>
#include <hip/hip_bf16.h>

#define NTOK 32768
#define NE   1024
#define DD   256
#define BM   16

typedef __attribute__((ext_vector_type(4))) float  f32x4;
typedef __attribute__((ext_vector_type(8))) short  bf16x8;

// ---- prep1: en10[row] = -10 * ||emb_row||^2 ----
__global__ __launch_bounds__(256) void prep_norm_kernel(
    const float* __restrict__ emb, float* __restrict__ en10)
{
    const int t = threadIdx.x;
    const int row = blockIdx.x * 4 + (t >> 6);   // one wave per row
    const int q = t & 63;
    f32x4 v = *(const f32x4*)(emb + (size_t)row * DD + q * 4);
    float ss = v.x * v.x + v.y * v.y + v.z * v.z + v.w * v.w;
#pragma unroll
    for (int off = 32; off; off >>= 1) ss += __shfl_xor(ss, off, 64);
    if (q == 0) en10[row] = -10.f * ss;
}

// ---- prep2: pack bf16(-2*emb) in MFMA B-fragment-linear order ----
// slot ((j2*8+kk)*64 + l) holds the 16B lane l=(lr,lg) consumes for
// col-block j2 (16 cols), k-chunk kk: emb[j2*16+lr][kk*32+lg*8 .. +8] * (-2)
__global__ __launch_bounds__(512) void prep_pack_kernel(
    const float* __restrict__ emb, __hip_bfloat16* __restrict__ embp)
{
    const int j2 = blockIdx.x;        // 0..63
    const int kk = threadIdx.x >> 6;  // 0..7
    const int l  = threadIdx.x & 63;
    const int lr = l & 15, lg = l >> 4;
    const float* src = emb + (size_t)(j2 * 16 + lr) * DD + kk * 32 + lg * 8;
    f32x4 a = *(const f32x4*)src;
    f32x4 b = *(const f32x4*)(src + 4);
    alignas(16) __hip_bfloat16 h[8];
    h[0] = __float2bfloat16(-2.f * a.x); h[1] = __float2bfloat16(-2.f * a.y);
    h[2] = __float2bfloat16(-2.f * a.z); h[3] = __float2bfloat16(-2.f * a.w);
    h[4] = __float2bfloat16(-2.f * b.x); h[5] = __float2bfloat16(-2.f * b.y);
    h[6] = __float2bfloat16(-2.f * b.z); h[7] = __float2bfloat16(-2.f * b.w);
    *(bf16x8*)(embp + ((size_t)(j2 * 8 + kk) * 64 + l) * 8) = *(const bf16x8*)h;
}

// ---- main: fused dist-GEMM + double-exp + row softmax ----
// block = 1024 threads (16 waves); tile = 16 rows x 1024 cols;
// wave w owns cols [w*64, w*64+64). B-loads are fragment-linear (coalesced 1KB).
__global__ __launch_bounds__(1024, 8) void sq_main_kernel(
    const float* __restrict__ z, const __hip_bfloat16* __restrict__ embp,
    const float* __restrict__ en10, float* __restrict__ out)
{
    __shared__ alignas(16) __hip_bfloat16 za[BM][DD + 8];
    __shared__ float zn10_s[BM];
    __shared__ float red[BM][16];

    const int t  = threadIdx.x;
    const int n0 = blockIdx.x * BM;
    const int w  = t >> 6;     // wave id 0..15  (stages row w; owns col block w)
    const int l  = t & 63;     // lane

    // ---- stage z tile: wave w stages row w (fp32 load, -10*norm, bf16 to LDS) ----
    {
        f32x4 v = *(const f32x4*)(z + (size_t)(n0 + w) * DD + l * 4);
        float ss = v.x * v.x + v.y * v.y + v.z * v.z + v.w * v.w;
#pragma unroll
        for (int off = 32; off; off >>= 1) ss += __shfl_xor(ss, off, 64);
        if (l == 0) zn10_s[w] = -10.f * ss;
        alignas(8) __hip_bfloat16 h[4];
        h[0] = __float2bfloat16(v.x); h[1] = __float2bfloat16(v.y);
        h[2] = __float2bfloat16(v.z); h[3] = __float2bfloat16(v.w);
        *(short4*)&za[w][l * 4] = *(const short4*)h;
    }
    __syncthreads();

    const int lr = l & 15, lg = l >> 4;   // A-row (B-col) / k-group

    // ---- A fragments: all 16 rows x full K in registers (32 VGPR) ----
    bf16x8 afrag[8];
#pragma unroll
    for (int kk = 0; kk < 8; ++kk)
        afrag[kk] = *(const bf16x8*)&za[lr][kk * 32 + lg * 8];

    // ---- GEMM: acc[j] over this wave's 64 cols; B from packed fragments ----
    f32x4 acc[4];
#pragma unroll
    for (int j = 0; j < 4; ++j) acc[j] = (f32x4){0.f, 0.f, 0.f, 0.f};

    const __hip_bfloat16* bbase = embp + ((size_t)(w * 4) * 8 + 0) * 64 * 8 + l * 8;
#pragma unroll
    for (int j = 0; j < 4; ++j) {
#pragma unroll
        for (int kk = 0; kk < 8; ++kk) {
            bf16x8 b = *(const bf16x8*)(bbase + (size_t)(j * 8 + kk) * 64 * 8);
            acc[j] = __builtin_amdgcn_mfma_f32_16x16x32_bf16(afrag[kk], b, acc[j], 0, 0, 0);
        }
    }

    // ---- epilogue: tt = -10*d ; u = 10*exp(tt) ; e = exp(u) ; u in (0,10] ----
    float zr10[4];
#pragma unroll
    for (int r = 0; r < 4; ++r) zr10[r] = zn10_s[lg * 4 + r];

    float sum[4] = {0.f, 0.f, 0.f, 0.f};
#pragma unroll
    for (int j = 0; j < 4; ++j) {
        const float ec10 = en10[w * 64 + j * 16 + lr];
#pragma unroll
        for (int r = 0; r < 4; ++r) {
            const float tt = fmaf(-10.0f, acc[j][r], zr10[r] + ec10);
            const float u  = 10.0f * __expf(tt);
            const float e  = __expf(u);
            acc[j][r] = e;
            sum[r] += e;
        }
    }
    // sum across the 16 lanes sharing lg (butterfly within 16-lane groups)
#pragma unroll
    for (int off = 1; off < 16; off <<= 1)
#pragma unroll
        for (int r = 0; r < 4; ++r) sum[r] += __shfl_xor(sum[r], off, 64);
    if (lr == 0)
#pragma unroll
        for (int r = 0; r < 4; ++r) red[lg * 4 + r][w] = sum[r];
    __syncthreads();

    float inv[4];
#pragma unroll
    for (int r = 0; r < 4; ++r) {
        const float* p = red[lg * 4 + r];
        float s = 0.f;
#pragma unroll
        for (int q = 0; q < 16; ++q) s += p[q];
        inv[r] = 1.0f / s;
    }

    // ---- store: per (j,r) a wave writes 4 x 64B contiguous segments ----
#pragma unroll
    for (int j = 0; j < 4; ++j) {
        const int col = w * 64 + j * 16 + lr;
#pragma unroll
        for (int r = 0; r < 4; ++r) {
            const int row = lg * 4 + r;
            out[(size_t)(n0 + row) * NE + col] = acc[j][r] * inv[r];
        }
    }
}

extern "C" void kernel_launch(void* const* d_in, const int* in_sizes, int n_in,
                              void* d_out, int out_size, void* d_ws, size_t ws_size,
                              hipStream_t stream) {
    (void)in_sizes; (void)n_in; (void)out_size; (void)ws_size;
    const float* z   = (const float*)d_in[0];
    const float* emb = (const float*)d_in[1];
    float* out = (float*)d_out;
    __hip_bfloat16* embp = (__hip_bfloat16*)d_ws;
    float* en10 = (float*)((char*)d_ws + (size_t)NE * DD * sizeof(__hip_bfloat16));

    hipLaunchKernelGGL(prep_norm_kernel, dim3(NE / 4), dim3(256), 0, stream,
                       emb, en10);
    hipLaunchKernelGGL(prep_pack_kernel, dim3(64), dim3(512), 0, stream,
                       emb, embp);
    hipLaunchKernelGGL(sq_main_kernel, dim3(NTOK / BM), dim3(1024), 0, stream,
                       z, embp, en10, out);
}